// Round 1
// baseline (794.589 us; speedup 1.0000x reference)
//
#include <hip/hip_runtime.h>
#include <math.h>

#define B_  32
#define C_  273
#define T_  4096
#define O_  270
#define D_  288
#define NF  12

// ---------------- kernel 0: heads [270][288] -> headsT [288][270] ----------------
__global__ __launch_bounds__(256) void k_transpose_heads(const float* __restrict__ heads,
                                                         float* __restrict__ headsT) {
    int idx = blockIdx.x * 256 + threadIdx.x;
    if (idx >= O_ * D_) return;
    int o = idx / D_;
    int d = idx - o * D_;
    headsT[d * O_ + o] = heads[idx];
}

// ---------------- kernel 1: fourier embedding -> emb [B*C][288] ----------------
__global__ void k_emb(const float* __restrict__ pos, float* __restrict__ emb) {
    int bc = blockIdx.x;          // 0 .. B*C-1
    int i  = threadIdx.x;         // 0 .. 143
    float px = pos[bc * 2 + 0] + 0.1f;
    float py = pos[bc * 2 + 1] + 0.1f;
    const float K = 5.235987755982989f;   // 2*pi / 1.2
    int fx = i / NF;
    int fy = i - fx * NF;
    float loc = px * (K * (float)fx) + py * (K * (float)fy);
    float s, c;
    sincosf(loc, &s, &c);
    emb[(size_t)bc * D_ + i]       = c;
    emb[(size_t)bc * D_ + 144 + i] = s;
}

// ---------------- kernel 2: scores scT[b][c][o] = emb[b,c,:] . heads[o,:] ----------------
#define CT 16
__global__ __launch_bounds__(256) void k_scores(const float* __restrict__ emb,
                                                const float* __restrict__ headsT,
                                                float* __restrict__ scT) {
    __shared__ float es[CT * D_];          // 18 KiB
    int b  = blockIdx.y;
    int c0 = blockIdx.x * CT;
    int nc = C_ - c0; if (nc > CT) nc = CT;
    int tid = threadIdx.x;

    const float* src = emb + ((size_t)b * C_ + c0) * D_;   // contiguous nc*288
    for (int k = tid; k < CT * D_; k += 256)
        es[k] = (k < nc * D_) ? src[k] : 0.0f;
    __syncthreads();

    for (int o = tid; o < O_; o += 256) {
        float acc[CT];
#pragma unroll
        for (int cc = 0; cc < CT; ++cc) acc[cc] = 0.0f;

        for (int d = 0; d < D_; d += 4) {
            float h0 = headsT[(d + 0) * O_ + o];
            float h1 = headsT[(d + 1) * O_ + o];
            float h2 = headsT[(d + 2) * O_ + o];
            float h3 = headsT[(d + 3) * O_ + o];
#pragma unroll
            for (int cc = 0; cc < CT; ++cc) {
                const float4 e = *(const float4*)&es[cc * D_ + d];
                acc[cc] = fmaf(e.x, h0, acc[cc]);
                acc[cc] = fmaf(e.y, h1, acc[cc]);
                acc[cc] = fmaf(e.z, h2, acc[cc]);
                acc[cc] = fmaf(e.w, h3, acc[cc]);
            }
        }
        for (int cc = 0; cc < nc; ++cc)
            scT[((size_t)b * C_ + c0 + cc) * O_ + o] = acc[cc];
    }
}

// ---------------- kernel 3: softmax over c (in place), scT -> weights ----------------
__global__ __launch_bounds__(320) void k_softmax(float* __restrict__ scT,
                                                 const unsigned char* __restrict__ mask) {
    int b = blockIdx.x;
    int o = threadIdx.x;
    if (o >= O_) return;

    float m = -INFINITY;
    for (int c = 0; c < C_; ++c) {
        float v = scT[((size_t)b * C_ + c) * O_ + o];
        if (mask[b * C_ + c]) v = -INFINITY;
        m = fmaxf(m, v);
    }
    float sum = 0.0f;
    for (int c = 0; c < C_; ++c) {
        if (mask[b * C_ + c]) continue;
        float v = scT[((size_t)b * C_ + c) * O_ + o];
        sum += __expf(v - m);
    }
    float inv = 1.0f / sum;
    for (int c = 0; c < C_; ++c) {
        size_t idx = ((size_t)b * C_ + c) * O_ + o;
        float v = scT[idx];
        float w = mask[b * C_ + c] ? 0.0f : __expf(v - m) * inv;
        scT[idx] = w;
    }
}

// ---------------- kernel 4: merge out[b][o][t] = sum_c w[b][c][o] * meg[b][c][t] ----------------
#define OT 30
#define CPAD 276   // 273 padded to multiple of 4 (16B rows for ds_read_b128)
__global__ __launch_bounds__(256) void k_merge(const float* __restrict__ meg,
                                               const float* __restrict__ wT,
                                               float* __restrict__ out) {
    __shared__ float wl[OT][CPAD];   // 33,120 B

    // XCD-aware decode: 1152 blocks = 32 b * 9 o-tiles * 4 t-tiles.
    // xcd = L & 7; each XCD owns 4 b's, all 36 tiles of a b consecutive.
    int L     = blockIdx.x;
    int xcd   = L & 7;
    int local = L >> 3;          // 0..143
    int bgrp  = local / 36;      // 0..3
    int tile  = local - bgrp * 36;
    int b  = bgrp * 8 + xcd;     // 0..31
    int ot = tile / 4;           // 0..8
    int tt = tile - ot * 4;      // 0..3

    int o0  = ot * OT;
    int t0  = tt * 1024;
    int tid = threadIdx.x;

    // load weight tile [OT][273]: semi-coalesced (30-wide segments over o)
    for (int idx = tid; idx < C_ * OT; idx += 256) {
        int cc = idx / OT;
        int oo = idx - cc * OT;
        wl[oo][cc] = wT[((size_t)b * C_ + cc) * O_ + o0 + oo];
    }
    __syncthreads();

    float4 acc[OT];
#pragma unroll
    for (int o = 0; o < OT; ++o) acc[o] = make_float4(0.f, 0.f, 0.f, 0.f);

    const float* mp = meg + (size_t)b * C_ * T_ + t0 + tid * 4;

    int c = 0;
    for (; c + 3 < C_; c += 4) {
        const float4 m0 = *(const float4*)(mp + (size_t)(c + 0) * T_);
        const float4 m1 = *(const float4*)(mp + (size_t)(c + 1) * T_);
        const float4 m2 = *(const float4*)(mp + (size_t)(c + 2) * T_);
        const float4 m3 = *(const float4*)(mp + (size_t)(c + 3) * T_);
#pragma unroll
        for (int o = 0; o < OT; ++o) {
            const float4 wv = *(const float4*)&wl[o][c];
            acc[o].x = fmaf(wv.x, m0.x, acc[o].x);
            acc[o].y = fmaf(wv.x, m0.y, acc[o].y);
            acc[o].z = fmaf(wv.x, m0.z, acc[o].z);
            acc[o].w = fmaf(wv.x, m0.w, acc[o].w);
            acc[o].x = fmaf(wv.y, m1.x, acc[o].x);
            acc[o].y = fmaf(wv.y, m1.y, acc[o].y);
            acc[o].z = fmaf(wv.y, m1.z, acc[o].z);
            acc[o].w = fmaf(wv.y, m1.w, acc[o].w);
            acc[o].x = fmaf(wv.z, m2.x, acc[o].x);
            acc[o].y = fmaf(wv.z, m2.y, acc[o].y);
            acc[o].z = fmaf(wv.z, m2.z, acc[o].z);
            acc[o].w = fmaf(wv.z, m2.w, acc[o].w);
            acc[o].x = fmaf(wv.w, m3.x, acc[o].x);
            acc[o].y = fmaf(wv.w, m3.y, acc[o].y);
            acc[o].z = fmaf(wv.w, m3.z, acc[o].z);
            acc[o].w = fmaf(wv.w, m3.w, acc[o].w);
        }
    }
    // tail: c = 272
    {
        const float4 m0 = *(const float4*)(mp + (size_t)c * T_);
#pragma unroll
        for (int o = 0; o < OT; ++o) {
            const float w = wl[o][c];
            acc[o].x = fmaf(w, m0.x, acc[o].x);
            acc[o].y = fmaf(w, m0.y, acc[o].y);
            acc[o].z = fmaf(w, m0.z, acc[o].z);
            acc[o].w = fmaf(w, m0.w, acc[o].w);
        }
    }

#pragma unroll
    for (int o = 0; o < OT; ++o) {
        *(float4*)&out[((size_t)b * O_ + o0 + o) * T_ + t0 + tid * 4] = acc[o];
    }
}

// ---------------- launcher ----------------
extern "C" void kernel_launch(void* const* d_in, const int* in_sizes, int n_in,
                              void* d_out, int out_size, void* d_ws, size_t ws_size,
                              hipStream_t stream) {
    const float*         meg  = (const float*)d_in[0];   // [B, C, T]
    const float*         pos  = (const float*)d_in[1];   // [B, C, 2]
    const float*         heads = (const float*)d_in[2];  // [O, D]
    const unsigned char* mask = (const unsigned char*)d_in[3]; // [B, C] bool
    float* out = (float*)d_out;                          // [B, O, T]

    // workspace layout
    char* ws = (char*)d_ws;
    float* headsT = (float*)ws;                               // 288*270*4 = 311,040 B
    float* emb    = (float*)(ws + 311296);                    // B*C*288*4 = 10,063,872 B
    float* wT     = (float*)(ws + 311296 + 10063872);         // B*C*270*4 = 9,434,880 B

    // 0. transpose heads
    k_transpose_heads<<<(O_ * D_ + 255) / 256, 256, 0, stream>>>(heads, headsT);
    // 1. fourier embedding
    k_emb<<<B_ * C_, 144, 0, stream>>>(pos, emb);
    // 2. scores (transposed layout [b][c][o])
    k_scores<<<dim3((C_ + CT - 1) / CT, B_), 256, 0, stream>>>(emb, headsT, wT);
    // 3. softmax over c (in place -> weights)
    k_softmax<<<B_, 320, 0, stream>>>(wT, mask);
    // 4. merge
    k_merge<<<B_ * 9 * 4, 256, 0, stream>>>(meg, wT, out);
}